// Round 5
// baseline (398.991 us; speedup 1.0000x reference)
//
#include <hip/hip_runtime.h>

typedef unsigned short u16;
using u16x4  = __attribute__((ext_vector_type(4))) unsigned short;
using u16x8  = __attribute__((ext_vector_type(8))) unsigned short;
using bf16x8 = __attribute__((ext_vector_type(8))) short;
using f32x4  = __attribute__((ext_vector_type(4))) float;
using f32x16 = __attribute__((ext_vector_type(16))) float;

// ---------- helpers ----------
__device__ __forceinline__ u16 f2bf(float f) {
  union { float f; unsigned u; } v; v.f = f;
  unsigned r = v.u + 0x7FFFu + ((v.u >> 16) & 1u);  // RNE (inputs bounded, no NaN)
  return (u16)(r >> 16);
}

__device__ __forceinline__ unsigned cvt_pk_bf16(float a, float b) {
  unsigned d;
  asm("v_cvt_pk_bf16_f32 %0, %1, %2" : "=v"(d) : "v"(a), "v"(b));
  return d;  // low16 = bf16(a), high16 = bf16(b)
}

// ---------- fused pre-pass: W transpose+convert AND x convert ----------
// blocks 0..8191: W [mat][i][h] fp32 -> blocked bf16 [mat][i/16][h][16]
//   element (i,h) -> (i>>4)*4096 + h*16 + (i&15)
// blocks 8192..8703: x fp32 -> bf16
__global__ __launch_bounds__(256) void prepass_k(
    const float* __restrict__ W1, const float* __restrict__ W2,
    u16* __restrict__ w1t, u16* __restrict__ w2t,
    const float* __restrict__ x, u16* __restrict__ xb) {
  __shared__ float tile[64][65];
  const int bid = blockIdx.x;
  const int t = threadIdx.x;
  if (bid >= 8192) {                   // x conversion
    int i = (bid - 8192) * 256 + t;
    float4 v = ((const float4*)x)[i];
    u16x4 u;
    u.x = f2bf(v.x); u.y = f2bf(v.y); u.z = f2bf(v.z); u.w = f2bf(v.w);
    ((u16x4*)xb)[i] = u;
    return;
  }
  const int mat = bid >> 4;
  const int tl  = bid & 15;
  const int i0 = (tl >> 2) * 64, h0 = (tl & 3) * 64;
  const float* src = (mat < 256) ? (W1 + mat * 65536) : (W2 + (mat - 256) * 65536);
  u16*       dst   = (mat < 256) ? (w1t + mat * 65536) : (w2t + (mat - 256) * 65536);
#pragma unroll
  for (int j = 0; j < 4; ++j) {
    int lin = j * 256 + t;
    int row = lin >> 4, c4 = lin & 15;
    float4 v = *(const float4*)(src + (i0 + row) * 256 + h0 + c4 * 4);
    tile[row][c4 * 4 + 0] = v.x; tile[row][c4 * 4 + 1] = v.y;
    tile[row][c4 * 4 + 2] = v.z; tile[row][c4 * 4 + 3] = v.w;
  }
  __syncthreads();
  const int col = t >> 2;            // h = h0 + col
  const int kk  = (t & 3) * 8;       // 0,8,16,24
#pragma unroll
  for (int p = 0; p < 2; ++p) {
    u16x8 o;
#pragma unroll
    for (int jj = 0; jj < 8; ++jj)
      o[jj] = f2bf(tile[p * 32 + kk + jj][col]);
    *(u16x8*)(dst + ((i0 >> 4) + 2 * p + (kk >> 4)) * 4096 + (h0 + col) * 16 + (kk & 8)) = o;
  }
}

// ---------- main fused kernel: persistent-c blocks, 256-row tiles, deep reg pipeline ----------
// Grid = 256 blocks (1 per CU), block owns ONE subcarrier c and loops over all 8
// 256-row batch tiles. 512 threads = 8 waves = 4 wq x 2 bh; wave = 2 m-frags x 4 n-frags.
// Persistence wins: (1) the W1 chunk-0..2 prefetch for iteration j+1 is issued during
// iteration j's phase-B tail (same data, same rotating register sets: (ch+3)&3 = 0,1,2
// for ch=13..15) -> the A-latency prologue stall is paid once, not 8x; (2) W1c/W2c stay
// L2-warm across iterations. T5: setprio(1) around each MFMA cluster (2 unsynced
// waves/SIMD = role diversity).
// Regs: 128 acc (AGPR) + 128 VGPR = 256 = exactly the 2-wave/SIMD budget.
__global__ __launch_bounds__(512, 2) void rf_main_k(
    const u16* __restrict__ xb, const u16* __restrict__ w1t, const u16* __restrict__ w2t,
    const float* __restrict__ b1, const float* __restrict__ b2,
    const float* __restrict__ w3, const float* __restrict__ b3,
    float* __restrict__ out) {
  __shared__ u16 sH[256 * 264];        // x-tile, then H1 (in place), stride 264

  const int bid  = blockIdx.x;         // 256 blocks, 1 per CU
  const int xcd  = bid & 7;
  const int c    = xcd * 32 + (bid >> 3);
  const int t    = threadIdx.x;
  const int lane = t & 63;
  const int w    = t >> 6;
  const int l31  = lane & 31;
  const int hi   = lane >> 5;
  const bool hiH = hi != 0;
  const int wq   = w & 3;              // 4 m-positions
  const int bh   = w >> 2;             // 2 n-halves
  const int m_base = wq * 64;

  const u16* w1c = w1t + c * 65536;
  const u16* w2c = w2t + c * 65536;
  const int aoff = (m_base + l31) * 16 + hi * 8;     // + ch*4096 + mi*512
  int bb[4];
#pragma unroll
  for (int nj = 0; nj < 4; ++nj)
    bb[nj] = (bh * 128 + nj * 32 + l31) * 264 + hi * 8;   // + ch*16
  const int bidx = __builtin_amdgcn_readfirstlane(c * 256 + m_base);

  f32x16 acc[2][4];
  bf16x8 aS[4][2];                     // A rotating sets (ch & 3), depth 3
  bf16x8 bS[2][4];                     // B rotating sets (ch & 1), depth 1

#define LOADA(dst, base)                                         \
  { dst[0] = *(const bf16x8*)(base);                             \
    dst[1] = *(const bf16x8*)((base) + 512); }

#define LOADB(dst, ch)                                           \
  { _Pragma("unroll")                                            \
    for (int _nj = 0; _nj < 4; ++_nj)                            \
      dst[_nj] = *(const bf16x8*)&sH[bb[_nj] + (ch) * 16]; }

#define COMPUTE(afr, bfr)                                        \
  { __builtin_amdgcn_s_setprio(1);                               \
    _Pragma("unroll")                                            \
    for (int _nj = 0; _nj < 4; ++_nj) {                          \
      acc[0][_nj] = __builtin_amdgcn_mfma_f32_32x32x16_bf16(afr[0], bfr[_nj], acc[0][_nj], 0, 0, 0); \
      acc[1][_nj] = __builtin_amdgcn_mfma_f32_32x32x16_bf16(afr[1], bfr[_nj], acc[1][_nj], 0, 0, 0); \
    }                                                            \
    __builtin_amdgcn_s_setprio(0); }

  // ---- one-time prologue: A chunks 0..2 of W1 in flight ----
  LOADA(aS[0], w1c + 0 * 4096 + aoff);
  LOADA(aS[1], w1c + 1 * 4096 + aoff);
  LOADA(aS[2], w1c + 2 * 4096 + aoff);

#pragma unroll 1
  for (int it = 0; it < 8; ++it) {
    const int b0 = it * 256;
    __syncthreads();                   // prev iter's sH readers (red/out) done

    // acc init = b1 bias (issue bias loads before the staging burst)
#pragma unroll
    for (int mi = 0; mi < 2; ++mi)
#pragma unroll
      for (int g = 0; g < 4; ++g) {
        f32x4 lo = *(const f32x4*)(b1 + bidx + mi * 32 + g * 8);
        f32x4 h4 = *(const f32x4*)(b1 + bidx + mi * 32 + g * 8 + 4);
#pragma unroll
        for (int r = 0; r < 4; ++r) {
          float v = hiH ? h4[r] : lo[r];
#pragma unroll
          for (int nj = 0; nj < 4; ++nj)
            acc[mi][nj][g * 4 + r] = v;
        }
      }

    // stage x-tile: 256 rows x 256 u16 -> sH stride 264
#pragma unroll
    for (int i = 0; i < 16; ++i) {
      int flat = i * 512 + t;
      int r = flat >> 5, s = flat & 31;
      u16x8 g = *(const u16x8*)(xb + (b0 + r) * 256 + s * 8);
      *(u16x8*)&sH[r * 264 + s * 8] = g;
    }
    __syncthreads();

    // ========== Phase A: H1^T = W1^T . x^T (+b1, relu) ==========
    LOADB(bS[0], 0);
#pragma unroll
    for (int ch = 0; ch < 16; ++ch) {
      // A(ch+3): last 3 iterations prefetch W2 chunks 0..2
      const u16* ab = (ch + 3 < 16) ? (w1c + (ch + 3) * 4096) : (w2c + (ch - 13) * 4096);
      LOADA(aS[(ch + 3) & 3], ab + aoff);
      if (ch + 1 < 16) LOADB(bS[(ch + 1) & 1], ch + 1);
      COMPUTE(aS[ch & 3], bS[ch & 1]);
    }

    // Phase A epilogue: relu -> bf16 H1, in place over sX
    __syncthreads();                   // all x reads retired
#pragma unroll
    for (int nj = 0; nj < 4; ++nj) {
      const int row = bh * 128 + nj * 32 + l31;
#pragma unroll
      for (int mi = 0; mi < 2; ++mi)
#pragma unroll
        for (int g = 0; g < 4; ++g) {
          float v0 = fmaxf(acc[mi][nj][g * 4 + 0], 0.f);
          float v1 = fmaxf(acc[mi][nj][g * 4 + 1], 0.f);
          float v2 = fmaxf(acc[mi][nj][g * 4 + 2], 0.f);
          float v3 = fmaxf(acc[mi][nj][g * 4 + 3], 0.f);
          uint2 p;
          p.x = cvt_pk_bf16(v0, v1);
          p.y = cvt_pk_bf16(v2, v3);
          *(uint2*)&sH[row * 264 + m_base + mi * 32 + g * 8 + 4 * hi] = p;
          acc[mi][nj][g * 4 + 0] = 0.f; acc[mi][nj][g * 4 + 1] = 0.f;
          acc[mi][nj][g * 4 + 2] = 0.f; acc[mi][nj][g * 4 + 3] = 0.f;
        }
    }
    __syncthreads();                   // H1 published

    // ========== Phase B: H2^T = W2^T . H1^T, bias+relu+dot(W3) in epilogue ==========
    LOADB(bS[0], 0);
#pragma unroll
    for (int ch = 0; ch < 16; ++ch) {
      // A(ch+3): last 3 iterations prefetch NEXT iteration's W1 chunks 0..2
      const u16* ab = (ch + 3 < 16) ? (w2c + (ch + 3) * 4096) : (w1c + (ch - 13) * 4096);
      LOADA(aS[(ch + 3) & 3], ab + aoff);
      if (ch + 1 < 16) LOADB(bS[(ch + 1) & 1], ch + 1);
      COMPUTE(aS[ch & 3], bS[ch & 1]);
    }

    // Phase B epilogue: out-col reduction fully in-lane (b2/w3 wave-uniform per reg)
    float part[4] = {0.f, 0.f, 0.f, 0.f};
#pragma unroll
    for (int mi = 0; mi < 2; ++mi)
#pragma unroll
      for (int g = 0; g < 4; ++g) {
        f32x4 blo = *(const f32x4*)(b2 + bidx + mi * 32 + g * 8);
        f32x4 bh4 = *(const f32x4*)(b2 + bidx + mi * 32 + g * 8 + 4);
        f32x4 wlo = *(const f32x4*)(w3 + bidx + mi * 32 + g * 8);
        f32x4 wh4 = *(const f32x4*)(w3 + bidx + mi * 32 + g * 8 + 4);
#pragma unroll
        for (int r = 0; r < 4; ++r) {
          float bv = hiH ? bh4[r] : blo[r];
          float wv = hiH ? wh4[r] : wlo[r];
#pragma unroll
          for (int nj = 0; nj < 4; ++nj)
            part[nj] += fmaxf(acc[mi][nj][g * 4 + r] + bv, 0.f) * wv;
        }
      }
    __syncthreads();                   // all sH reads retired -> safe to alias red
    float* red = (float*)sH;           // 8 x 256 f32 = 8 KB, aliased into sH
#pragma unroll
    for (int nj = 0; nj < 4; ++nj)
      red[(wq * 2 + hi) * 256 + bh * 128 + nj * 32 + l31] = part[nj];
    __syncthreads();
    if (t < 256) {
      float v = b3[c];
#pragma unroll
      for (int k = 0; k < 8; ++k) v += red[k * 256 + t];
      out[(b0 + t) * 256 + c] = v;
    }
  }
#undef LOADA
#undef LOADB
#undef COMPUTE
}

// ---------- launcher ----------
extern "C" void kernel_launch(void* const* d_in, const int* in_sizes, int n_in,
                              void* d_out, int out_size, void* d_ws, size_t ws_size,
                              hipStream_t stream) {
  const float* x  = (const float*)d_in[0];
  const float* W1 = (const float*)d_in[1];
  const float* b1 = (const float*)d_in[2];
  const float* W2 = (const float*)d_in[3];
  const float* b2 = (const float*)d_in[4];
  const float* W3 = (const float*)d_in[5];
  const float* b3 = (const float*)d_in[6];
  float* out = (float*)d_out;

  char* ws = (char*)d_ws;
  u16* xb  = (u16*)ws;                                   // 1 MB
  u16* w1t = (u16*)(ws + (1u << 20));                    // 32 MB
  u16* w2t = (u16*)(ws + (1u << 20) + (32u << 20));      // 32 MB

  prepass_k <<<8704, 256, 0, stream>>>(W1, W2, w1t, w2t, x, xb);
  rf_main_k <<< 256, 512, 0, stream>>>(xb, w1t, w2t, b1, b2, W3, b3, out);
}

// Round 7
// 307.103 us; speedup vs baseline: 1.2992x; 1.2992x over previous
//
#include <hip/hip_runtime.h>

typedef unsigned short u16;
using u16x4  = __attribute__((ext_vector_type(4))) unsigned short;
using u16x8  = __attribute__((ext_vector_type(8))) unsigned short;
using bf16x8 = __attribute__((ext_vector_type(8))) short;
using f32x4  = __attribute__((ext_vector_type(4))) float;
using f32x16 = __attribute__((ext_vector_type(16))) float;

// ---------- helpers ----------
__device__ __forceinline__ u16 f2bf(float f) {
  union { float f; unsigned u; } v; v.f = f;
  unsigned r = v.u + 0x7FFFu + ((v.u >> 16) & 1u);  // RNE (inputs bounded, no NaN)
  return (u16)(r >> 16);
}

__device__ __forceinline__ unsigned cvt_pk_bf16(float a, float b) {
  unsigned d;
  asm("v_cvt_pk_bf16_f32 %0, %1, %2" : "=v"(d) : "v"(a), "v"(b));
  return d;  // low16 = bf16(a), high16 = bf16(b)
}

// ---------- fused pre-pass: W transpose+convert AND x convert ----------
// blocks 0..8191: W [mat][i][h] fp32 -> blocked bf16 [mat][i/16][h][16]
//   element (i,h) -> (i>>4)*4096 + h*16 + (i&15)
// blocks 8192..8703: x fp32 -> bf16
__global__ __launch_bounds__(256) void prepass_k(
    const float* __restrict__ W1, const float* __restrict__ W2,
    u16* __restrict__ w1t, u16* __restrict__ w2t,
    const float* __restrict__ x, u16* __restrict__ xb) {
  __shared__ float tile[64][65];
  const int bid = blockIdx.x;
  const int t = threadIdx.x;
  if (bid >= 8192) {                   // x conversion
    int i = (bid - 8192) * 256 + t;
    float4 v = ((const float4*)x)[i];
    u16x4 u;
    u.x = f2bf(v.x); u.y = f2bf(v.y); u.z = f2bf(v.z); u.w = f2bf(v.w);
    ((u16x4*)xb)[i] = u;
    return;
  }
  const int mat = bid >> 4;
  const int tl  = bid & 15;
  const int i0 = (tl >> 2) * 64, h0 = (tl & 3) * 64;
  const float* src = (mat < 256) ? (W1 + mat * 65536) : (W2 + (mat - 256) * 65536);
  u16*       dst   = (mat < 256) ? (w1t + mat * 65536) : (w2t + (mat - 256) * 65536);
#pragma unroll
  for (int j = 0; j < 4; ++j) {
    int lin = j * 256 + t;
    int row = lin >> 4, c4 = lin & 15;
    float4 v = *(const float4*)(src + (i0 + row) * 256 + h0 + c4 * 4);
    tile[row][c4 * 4 + 0] = v.x; tile[row][c4 * 4 + 1] = v.y;
    tile[row][c4 * 4 + 2] = v.z; tile[row][c4 * 4 + 3] = v.w;
  }
  __syncthreads();
  const int col = t >> 2;            // h = h0 + col
  const int kk  = (t & 3) * 8;       // 0,8,16,24
#pragma unroll
  for (int p = 0; p < 2; ++p) {
    u16x8 o;
#pragma unroll
    for (int jj = 0; jj < 8; ++jj)
      o[jj] = f2bf(tile[p * 32 + kk + jj][col]);
    *(u16x8*)(dst + ((i0 >> 4) + 2 * p + (kk >> 4)) * 4096 + (h0 + col) * 16 + (kk & 8)) = o;
  }
}

// ---------- main fused kernel: R1 structure + prefetch depth + setprio ----------
// Block = (subcarrier c, 128-row batch tile). 512 threads = 8 waves = 4 wq x 2 bh.
// Wave: 2 m-frags (m_base = wq*64, +0/+32) x 2 n-frags (rows bh*64 + nj*32).
// Grid mapping (R1, measured-best): same-c blocks cluster on one XCD -> W L2-resident.
// DO NOT make blocks persistent (R5: L2 thrash, FETCH 38->508 MB).
// Deltas vs R1 (157 us): A prefetch depth 2 (3 rotating reg sets, full unroll,
// compile-time %3), B prefetch depth 1 (ping-pong), setprio(1) around MFMA clusters.
// SET ALIGNMENT (R6 bug): phase A tail puts W2 chunk j in aS[(j+1)%3] (ch=14 ->
// aS[1], ch=15 -> aS[2]); phase B therefore consumes aS[(ch+1)%3] and prefetches
// chunk ch+2 into aS[ch%3] (= ((ch+2)+1)%3). Hazards: write set ch%3 != read set
// (ch+1)%3; chunk j written at it j-2, read at it j.
// Regs: 64 acc + 24 A + 16 B + addressing ~= 124 <= 128 -> 4 waves/SIMD holds.
__global__ __launch_bounds__(512, 4) void rf_main_k(
    const u16* __restrict__ xb, const u16* __restrict__ w1t, const u16* __restrict__ w2t,
    const float* __restrict__ b1, const float* __restrict__ b2,
    const float* __restrict__ w3, const float* __restrict__ b3,
    float* __restrict__ out) {
  __shared__ u16 sH[128 * 264];        // x-tile, then H1 (in place), stride 264
  __shared__ float red[8 * 128];

  const int bid  = blockIdx.x;
  const int xcd  = bid & 7;
  const int j8   = bid >> 3;
  const int c    = xcd * 32 + (j8 >> 4);
  const int b0   = (j8 & 15) * 128;
  const int t    = threadIdx.x;
  const int lane = t & 63;
  const int w    = t >> 6;
  const int l31  = lane & 31;
  const int hi   = lane >> 5;
  const bool hiH = hi != 0;
  const int wq   = w & 3;
  const int bh   = w >> 2;
  const int m_base = wq * 64;
  const int n_base = bh * 64;

  const u16* w1c = w1t + c * 65536;
  const u16* w2c = w2t + c * 65536;
  const int aoff  = (m_base + l31) * 16 + hi * 8;          // + ch*4096 + mi*512
  const int bbase = (n_base + l31) * 264 + hi * 8;         // + ch*16 (+8448 for nj=1)
  const int bidx  = __builtin_amdgcn_readfirstlane(c * 256 + m_base);

  f32x16 acc[2][2];
  bf16x8 aS[3][2];                     // A rotating sets, depth 2
  bf16x8 bS[2][2];                     // B ping-pong, depth 1

#define LOADA(dst, base)                                         \
  { dst[0] = *(const bf16x8*)(base);                             \
    dst[1] = *(const bf16x8*)((base) + 512); }

#define LOADB(dst, ch)                                           \
  { dst[0] = *(const bf16x8*)&sH[bbase + (ch) * 16];             \
    dst[1] = *(const bf16x8*)&sH[bbase + (ch) * 16 + 8448]; }

#define COMPUTE(afr, bfr)                                        \
  { __builtin_amdgcn_s_setprio(1);                               \
    acc[0][0] = __builtin_amdgcn_mfma_f32_32x32x16_bf16(afr[0], bfr[0], acc[0][0], 0, 0, 0); \
    acc[1][0] = __builtin_amdgcn_mfma_f32_32x32x16_bf16(afr[1], bfr[0], acc[1][0], 0, 0, 0); \
    acc[0][1] = __builtin_amdgcn_mfma_f32_32x32x16_bf16(afr[0], bfr[1], acc[0][1], 0, 0, 0); \
    acc[1][1] = __builtin_amdgcn_mfma_f32_32x32x16_bf16(afr[1], bfr[1], acc[1][1], 0, 0, 0); \
    __builtin_amdgcn_s_setprio(0); }

#define INIT_ACC(bp)                                             \
  { _Pragma("unroll")                                            \
    for (int _mi = 0; _mi < 2; ++_mi) {                          \
      _Pragma("unroll")                                          \
      for (int _g = 0; _g < 4; ++_g) {                           \
        f32x4 _lo = *(const f32x4*)((bp) + bidx + _mi * 32 + _g * 8);     \
        f32x4 _h4 = *(const f32x4*)((bp) + bidx + _mi * 32 + _g * 8 + 4); \
        _Pragma("unroll")                                        \
        for (int _r = 0; _r < 4; ++_r) {                         \
          float _v = hiH ? _h4[_r] : _lo[_r];                    \
          acc[_mi][0][_g * 4 + _r] = _v;                         \
          acc[_mi][1][_g * 4 + _r] = _v;                         \
        } } } }

  // ---- prologue: A chunks 0,1 of W1 in flight; stage x; bias-init acc ----
  LOADA(aS[0], w1c + 0 * 4096 + aoff);
  LOADA(aS[1], w1c + 1 * 4096 + aoff);

#pragma unroll
  for (int i = 0; i < 8; ++i) {
    int flat = i * 512 + t;
    int r = flat >> 5, s = flat & 31;
    u16x8 g = *(const u16x8*)(xb + (b0 + r) * 256 + s * 8);
    *(u16x8*)&sH[r * 264 + s * 8] = g;
  }
  INIT_ACC(b1);
  __syncthreads();

  // ========== Phase A: H1^T = W1^T . x^T (+b1, relu), barrier-free K-loop ==========
  // sets: prologue ch0->aS[0], ch1->aS[1]; consume aS[ch%3], load chunk ch+2 ->
  // aS[(ch+2)%3]; tail (ch=14,15) prefetches W2 chunk 0->aS[1], chunk 1->aS[2].
  LOADB(bS[0], 0);
#pragma unroll
  for (int ch = 0; ch < 16; ++ch) {
    const u16* ab = (ch + 2 < 16) ? (w1c + (ch + 2) * 4096) : (w2c + (ch - 14) * 4096);
    LOADA(aS[(ch + 2) % 3], ab + aoff);
    if (ch + 1 < 16) LOADB(bS[(ch + 1) & 1], ch + 1);
    COMPUTE(aS[ch % 3], bS[ch & 1]);
  }

  // Phase A epilogue: relu -> bf16 H1, in place over sX (b64 stores, in-lane packing)
  __syncthreads();                     // all x reads retired
#pragma unroll
  for (int mi = 0; mi < 2; ++mi)
#pragma unroll
    for (int nj = 0; nj < 2; ++nj) {
      const int row = n_base + nj * 32 + l31;
#pragma unroll
      for (int g = 0; g < 4; ++g) {
        float v0 = fmaxf(acc[mi][nj][g * 4 + 0], 0.f);
        float v1 = fmaxf(acc[mi][nj][g * 4 + 1], 0.f);
        float v2 = fmaxf(acc[mi][nj][g * 4 + 2], 0.f);
        float v3 = fmaxf(acc[mi][nj][g * 4 + 3], 0.f);
        uint2 p;
        p.x = cvt_pk_bf16(v0, v1);
        p.y = cvt_pk_bf16(v2, v3);
        *(uint2*)&sH[row * 264 + m_base + mi * 32 + g * 8 + 4 * hi] = p;
      }
    }
  INIT_ACC(b2);
  __syncthreads();                     // H1 published

  // ========== Phase B: H2^T = W2^T . H1^T (+b2, relu), then in-lane dot W3 ==========
  // W2 chunk j lives in aS[(j+1)%3] -> consume aS[(ch+1)%3], load chunk ch+2
  // into aS[ch%3] (set read last iteration; write-after-read in program order).
  LOADB(bS[0], 0);
#pragma unroll
  for (int ch = 0; ch < 16; ++ch) {
    if (ch + 2 < 16) LOADA(aS[ch % 3], w2c + (ch + 2) * 4096 + aoff);
    if (ch + 1 < 16) LOADB(bS[(ch + 1) & 1], ch + 1);
    COMPUTE(aS[(ch + 1) % 3], bS[ch & 1]);
  }

  // Phase B epilogue: out-col reduction fully in-lane (w3 wave-uniform per reg)
  float part0 = 0.f, part1 = 0.f;
#pragma unroll
  for (int mi = 0; mi < 2; ++mi)
#pragma unroll
    for (int g = 0; g < 4; ++g) {
      f32x4 wlo = *(const f32x4*)(w3 + bidx + mi * 32 + g * 8);
      f32x4 whi = *(const f32x4*)(w3 + bidx + mi * 32 + g * 8 + 4);
#pragma unroll
      for (int r = 0; r < 4; ++r) {
        float wv = hiH ? whi[r] : wlo[r];
        part0 += fmaxf(acc[mi][0][g * 4 + r], 0.f) * wv;
        part1 += fmaxf(acc[mi][1][g * 4 + r], 0.f) * wv;
      }
    }
  red[(wq * 2 + hi) * 128 + n_base + l31]      = part0;
  red[(wq * 2 + hi) * 128 + n_base + 32 + l31] = part1;
  __syncthreads();
  if (t < 128) {
    float v = b3[c];
#pragma unroll
    for (int k = 0; k < 8; ++k) v += red[k * 128 + t];
    out[(b0 + t) * 256 + c] = v;
  }
#undef LOADA
#undef LOADB
#undef COMPUTE
#undef INIT_ACC
}

// ---------- launcher ----------
extern "C" void kernel_launch(void* const* d_in, const int* in_sizes, int n_in,
                              void* d_out, int out_size, void* d_ws, size_t ws_size,
                              hipStream_t stream) {
  const float* x  = (const float*)d_in[0];
  const float* W1 = (const float*)d_in[1];
  const float* b1 = (const float*)d_in[2];
  const float* W2 = (const float*)d_in[3];
  const float* b2 = (const float*)d_in[4];
  const float* W3 = (const float*)d_in[5];
  const float* b3 = (const float*)d_in[6];
  float* out = (float*)d_out;

  char* ws = (char*)d_ws;
  u16* xb  = (u16*)ws;                                   // 1 MB
  u16* w1t = (u16*)(ws + (1u << 20));                    // 32 MB
  u16* w2t = (u16*)(ws + (1u << 20) + (32u << 20));      // 32 MB

  prepass_k <<<8704, 256, 0, stream>>>(W1, W2, w1t, w2t, x, xb);
  rf_main_k <<<4096, 512, 0, stream>>>(xb, w1t, w2t, b1, b2, W3, b3, out);
}

// Round 8
// 299.229 us; speedup vs baseline: 1.3334x; 1.0263x over previous
//
#include <hip/hip_runtime.h>

typedef unsigned short u16;
using u16x4  = __attribute__((ext_vector_type(4))) unsigned short;
using u16x8  = __attribute__((ext_vector_type(8))) unsigned short;
using bf16x8 = __attribute__((ext_vector_type(8))) short;
using f32x4  = __attribute__((ext_vector_type(4))) float;
using f32x16 = __attribute__((ext_vector_type(16))) float;

// ---------- helpers ----------
__device__ __forceinline__ u16 f2bf(float f) {
  union { float f; unsigned u; } v; v.f = f;
  unsigned r = v.u + 0x7FFFu + ((v.u >> 16) & 1u);  // RNE (inputs bounded, no NaN)
  return (u16)(r >> 16);
}

__device__ __forceinline__ unsigned cvt_pk_bf16(float a, float b) {
  unsigned d;
  asm("v_cvt_pk_bf16_f32 %0, %1, %2" : "=v"(d) : "v"(a), "v"(b));
  return d;  // low16 = bf16(a), high16 = bf16(b)
}

// ---------- fused pre-pass (LDS-free): W transpose+convert AND x convert ----------
// W layout: element (i,h) -> (i>>4)*4096 + h*16 + (i&15).
// blocks 0..8191: thread (bid,t) owns (mat = bid>>4, ib = bid&15, h = t):
//   reads W[mat][ib*16+j][h], j=0..15 -- each j is 64 consecutive floats across the
//   wave = 256 B coalesced segments; 16 independent loads/thread (deep MLP, no LDS,
//   no barrier); packs via v_cvt_pk_bf16_f32; writes 32 B contiguous per thread
//   (dense 2 KB per wave).
// blocks 8192..8703: x fp32 -> bf16.
__global__ __launch_bounds__(256) void prepass_k(
    const float* __restrict__ W1, const float* __restrict__ W2,
    u16* __restrict__ w1t, u16* __restrict__ w2t,
    const float* __restrict__ x, u16* __restrict__ xb) {
  const int bid = blockIdx.x;
  const int t = threadIdx.x;
  if (bid >= 8192) {                   // x conversion
    int i = (bid - 8192) * 256 + t;
    float4 v = ((const float4*)x)[i];
    u16x4 u;
    u.x = f2bf(v.x); u.y = f2bf(v.y); u.z = f2bf(v.z); u.w = f2bf(v.w);
    ((u16x4*)xb)[i] = u;
    return;
  }
  const int mat = bid >> 4;            // 0..511
  const int ib  = bid & 15;            // i-block (16 rows)
  const float* src = (mat < 256) ? (W1 + mat * 65536) : (W2 + (mat - 256) * 65536);
  u16*       dst   = (mat < 256) ? (w1t + mat * 65536) : (w2t + (mat - 256) * 65536);
  const int i0 = ib * 16;

  float r[16];
#pragma unroll
  for (int j = 0; j < 16; ++j)
    r[j] = src[(i0 + j) * 256 + t];    // coalesced across wave (consecutive t)

  uint4 lo, hi;
  lo.x = cvt_pk_bf16(r[0],  r[1]);  lo.y = cvt_pk_bf16(r[2],  r[3]);
  lo.z = cvt_pk_bf16(r[4],  r[5]);  lo.w = cvt_pk_bf16(r[6],  r[7]);
  hi.x = cvt_pk_bf16(r[8],  r[9]);  hi.y = cvt_pk_bf16(r[10], r[11]);
  hi.z = cvt_pk_bf16(r[12], r[13]); hi.w = cvt_pk_bf16(r[14], r[15]);
  u16* o = dst + ib * 4096 + t * 16;   // (i>>4)*4096 + h*16 + (i&15)
  *(uint4*)(o)     = lo;               // i&15 = 0..7
  *(uint4*)(o + 8) = hi;               // i&15 = 8..15
}

// ---------- main fused kernel: R7, FROZEN (structural plateau ~36% MFMA pipe) ----------
// Block = (subcarrier c, 128-row batch tile). 512 threads = 8 waves = 4 wq x 2 bh.
// Wave: 2 m-frags (m_base = wq*64, +0/+32) x 2 n-frags (rows bh*64 + nj*32).
// Grid mapping: same-c blocks cluster on one XCD -> W L2-resident. DO NOT make
// blocks persistent (R5: L2 thrash, FETCH 38->508 MB). A depth-2 register pipeline
// (3 rotating sets), B ping-pong, setprio around MFMA clusters (R7: 153 us, best).
// SET ALIGNMENT: phase A tail puts W2 chunk j in aS[(j+1)%3]; phase B consumes
// aS[(ch+1)%3] and prefetches chunk ch+2 into aS[ch%3].
// Regs: 64 acc + 24 A + 16 B + addressing -> 4 waves/SIMD, 2 blocks/CU.
__global__ __launch_bounds__(512, 4) void rf_main_k(
    const u16* __restrict__ xb, const u16* __restrict__ w1t, const u16* __restrict__ w2t,
    const float* __restrict__ b1, const float* __restrict__ b2,
    const float* __restrict__ w3, const float* __restrict__ b3,
    float* __restrict__ out) {
  __shared__ u16 sH[128 * 264];        // x-tile, then H1 (in place), stride 264
  __shared__ float red[8 * 128];

  const int bid  = blockIdx.x;
  const int xcd  = bid & 7;
  const int j8   = bid >> 3;
  const int c    = xcd * 32 + (j8 >> 4);
  const int b0   = (j8 & 15) * 128;
  const int t    = threadIdx.x;
  const int lane = t & 63;
  const int w    = t >> 6;
  const int l31  = lane & 31;
  const int hi   = lane >> 5;
  const bool hiH = hi != 0;
  const int wq   = w & 3;
  const int bh   = w >> 2;
  const int m_base = wq * 64;
  const int n_base = bh * 64;

  const u16* w1c = w1t + c * 65536;
  const u16* w2c = w2t + c * 65536;
  const int aoff  = (m_base + l31) * 16 + hi * 8;          // + ch*4096 + mi*512
  const int bbase = (n_base + l31) * 264 + hi * 8;         // + ch*16 (+8448 for nj=1)
  const int bidx  = __builtin_amdgcn_readfirstlane(c * 256 + m_base);

  f32x16 acc[2][2];
  bf16x8 aS[3][2];                     // A rotating sets, depth 2
  bf16x8 bS[2][2];                     // B ping-pong, depth 1

#define LOADA(dst, base)                                         \
  { dst[0] = *(const bf16x8*)(base);                             \
    dst[1] = *(const bf16x8*)((base) + 512); }

#define LOADB(dst, ch)                                           \
  { dst[0] = *(const bf16x8*)&sH[bbase + (ch) * 16];             \
    dst[1] = *(const bf16x8*)&sH[bbase + (ch) * 16 + 8448]; }

#define COMPUTE(afr, bfr)                                        \
  { __builtin_amdgcn_s_setprio(1);                               \
    acc[0][0] = __builtin_amdgcn_mfma_f32_32x32x16_bf16(afr[0], bfr[0], acc[0][0], 0, 0, 0); \
    acc[1][0] = __builtin_amdgcn_mfma_f32_32x32x16_bf16(afr[1], bfr[0], acc[1][0], 0, 0, 0); \
    acc[0][1] = __builtin_amdgcn_mfma_f32_32x32x16_bf16(afr[0], bfr[1], acc[0][1], 0, 0, 0); \
    acc[1][1] = __builtin_amdgcn_mfma_f32_32x32x16_bf16(afr[1], bfr[1], acc[1][1], 0, 0, 0); \
    __builtin_amdgcn_s_setprio(0); }

#define INIT_ACC(bp)                                             \
  { _Pragma("unroll")                                            \
    for (int _mi = 0; _mi < 2; ++_mi) {                          \
      _Pragma("unroll")                                          \
      for (int _g = 0; _g < 4; ++_g) {                           \
        f32x4 _lo = *(const f32x4*)((bp) + bidx + _mi * 32 + _g * 8);     \
        f32x4 _h4 = *(const f32x4*)((bp) + bidx + _mi * 32 + _g * 8 + 4); \
        _Pragma("unroll")                                        \
        for (int _r = 0; _r < 4; ++_r) {                         \
          float _v = hiH ? _h4[_r] : _lo[_r];                    \
          acc[_mi][0][_g * 4 + _r] = _v;                         \
          acc[_mi][1][_g * 4 + _r] = _v;                         \
        } } } }

  // ---- prologue: A chunks 0,1 of W1 in flight; stage x; bias-init acc ----
  LOADA(aS[0], w1c + 0 * 4096 + aoff);
  LOADA(aS[1], w1c + 1 * 4096 + aoff);

#pragma unroll
  for (int i = 0; i < 8; ++i) {
    int flat = i * 512 + t;
    int r = flat >> 5, s = flat & 31;
    u16x8 g = *(const u16x8*)(xb + (b0 + r) * 256 + s * 8);
    *(u16x8*)&sH[r * 264 + s * 8] = g;
  }
  INIT_ACC(b1);
  __syncthreads();

  // ========== Phase A: H1^T = W1^T . x^T (+b1, relu), barrier-free K-loop ==========
  LOADB(bS[0], 0);
#pragma unroll
  for (int ch = 0; ch < 16; ++ch) {
    const u16* ab = (ch + 2 < 16) ? (w1c + (ch + 2) * 4096) : (w2c + (ch - 14) * 4096);
    LOADA(aS[(ch + 2) % 3], ab + aoff);
    if (ch + 1 < 16) LOADB(bS[(ch + 1) & 1], ch + 1);
    COMPUTE(aS[ch % 3], bS[ch & 1]);
  }

  // Phase A epilogue: relu -> bf16 H1, in place over sX (b64 stores, in-lane packing)
  __syncthreads();                     // all x reads retired
#pragma unroll
  for (int mi = 0; mi < 2; ++mi)
#pragma unroll
    for (int nj = 0; nj < 2; ++nj) {
      const int row = n_base + nj * 32 + l31;
#pragma unroll
      for (int g = 0; g < 4; ++g) {
        float v0 = fmaxf(acc[mi][nj][g * 4 + 0], 0.f);
        float v1 = fmaxf(acc[mi][nj][g * 4 + 1], 0.f);
        float v2 = fmaxf(acc[mi][nj][g * 4 + 2], 0.f);
        float v3 = fmaxf(acc[mi][nj][g * 4 + 3], 0.f);
        uint2 p;
        p.x = cvt_pk_bf16(v0, v1);
        p.y = cvt_pk_bf16(v2, v3);
        *(uint2*)&sH[row * 264 + m_base + mi * 32 + g * 8 + 4 * hi] = p;
      }
    }
  INIT_ACC(b2);
  __syncthreads();                     // H1 published

  // ========== Phase B: H2^T = W2^T . H1^T (+b2, relu), then in-lane dot W3 ==========
  LOADB(bS[0], 0);
#pragma unroll
  for (int ch = 0; ch < 16; ++ch) {
    if (ch + 2 < 16) LOADA(aS[ch % 3], w2c + (ch + 2) * 4096 + aoff);
    if (ch + 1 < 16) LOADB(bS[(ch + 1) & 1], ch + 1);
    COMPUTE(aS[(ch + 1) % 3], bS[ch & 1]);
  }

  // Phase B epilogue: out-col reduction fully in-lane (w3 wave-uniform per reg)
  float part0 = 0.f, part1 = 0.f;
#pragma unroll
  for (int mi = 0; mi < 2; ++mi)
#pragma unroll
    for (int g = 0; g < 4; ++g) {
      f32x4 wlo = *(const f32x4*)(w3 + bidx + mi * 32 + g * 8);
      f32x4 whi = *(const f32x4*)(w3 + bidx + mi * 32 + g * 8 + 4);
#pragma unroll
      for (int r = 0; r < 4; ++r) {
        float wv = hiH ? whi[r] : wlo[r];
        part0 += fmaxf(acc[mi][0][g * 4 + r], 0.f) * wv;
        part1 += fmaxf(acc[mi][1][g * 4 + r], 0.f) * wv;
      }
    }
  red[(wq * 2 + hi) * 128 + n_base + l31]      = part0;
  red[(wq * 2 + hi) * 128 + n_base + 32 + l31] = part1;
  __syncthreads();
  if (t < 128) {
    float v = b3[c];
#pragma unroll
    for (int k = 0; k < 8; ++k) v += red[k * 128 + t];
    out[(b0 + t) * 256 + c] = v;
  }
#undef LOADA
#undef LOADB
#undef COMPUTE
#undef INIT_ACC
}

// ---------- launcher ----------
extern "C" void kernel_launch(void* const* d_in, const int* in_sizes, int n_in,
                              void* d_out, int out_size, void* d_ws, size_t ws_size,
                              hipStream_t stream) {
  const float* x  = (const float*)d_in[0];
  const float* W1 = (const float*)d_in[1];
  const float* b1 = (const float*)d_in[2];
  const float* W2 = (const float*)d_in[3];
  const float* b2 = (const float*)d_in[4];
  const float* W3 = (const float*)d_in[5];
  const float* b3 = (const float*)d_in[6];
  float* out = (float*)d_out;

  char* ws = (char*)d_ws;
  u16* xb  = (u16*)ws;                                   // 1 MB
  u16* w1t = (u16*)(ws + (1u << 20));                    // 32 MB
  u16* w2t = (u16*)(ws + (1u << 20) + (32u << 20));      // 32 MB

  prepass_k <<<8704, 256, 0, stream>>>(W1, W2, w1t, w2t, x, xb);
  rf_main_k <<<4096, 512, 0, stream>>>(xb, w1t, w2t, b1, b2, W3, b3, out);
}